// Round 4
// baseline (726.986 us; speedup 1.0000x reference)
//
#include <hip/hip_runtime.h>

#define EPS 1e-4f

constexpr int Bn = 64;
constexpr int Nn = 1024;
constexpr int Mn = 1024;
constexpr int NSPLIT = 16;          // fuse0 row chunks -> CHUNK=64 rows
constexpr int CHUNK  = Nn / NSPLIT; // 64
constexpr int SLOT0  = 2 * NSPLIT;  // 32 partial slots/sample (fuse0)
constexpr int SLOT1  = 64;          // partial slots/sample (fused row+col pass)

// ---- bf16 helpers (values positive finite; round-to-nearest-even) ----
__device__ __forceinline__ unsigned pk2(float a, float b) {
    unsigned ua = __float_as_uint(a); ua = (ua + 0x7fffu + ((ua >> 16) & 1u)) >> 16;
    unsigned ub = __float_as_uint(b); ub = (ub + 0x7fffu + ((ub >> 16) & 1u)) >> 16;
    return ua | (ub << 16);
}
__device__ __forceinline__ float lo16(unsigned v) { return __uint_as_float(v << 16); }
__device__ __forceinline__ float hi16(unsigned v) { return __uint_as_float(v & 0xffff0000u); }

// ---- pass 0 fused: unmasked col sums over ALL rows (f32) + compress s+eps
// -> bf16 sc for VALID rows only (rows >= nrows are dead after iteration 0).
__global__ __launch_bounds__(256) void fuse0_kernel(
        const float* __restrict__ s, unsigned short* __restrict__ sc,
        float* __restrict__ p, const int* __restrict__ nrows) {
    const int b = blockIdx.x, sp = blockIdx.y;
    const int t = threadIdx.x, half = t >> 7, tc = t & 127;
    const int nr = nrows[b];
    float acc[8];
    #pragma unroll
    for (int k = 0; k < 8; ++k) acc[k] = 0.f;
    for (int j = 0; j < CHUNK; j += 2) {
        const int n = sp * CHUNK + j + half;
        const size_t roff = ((size_t)b * Nn + n) * Mn;
        const float4* src = reinterpret_cast<const float4*>(s + roff) + 2 * tc;
        float4 v0 = src[0], v1 = src[1];
        v0.x += EPS; v0.y += EPS; v0.z += EPS; v0.w += EPS;
        v1.x += EPS; v1.y += EPS; v1.z += EPS; v1.w += EPS;
        acc[0] += v0.x; acc[1] += v0.y; acc[2] += v0.z; acc[3] += v0.w;
        acc[4] += v1.x; acc[5] += v1.y; acc[6] += v1.z; acc[7] += v1.w;
        if (n < nr) {
            uint4 w = { pk2(v0.x, v0.y), pk2(v0.z, v0.w),
                        pk2(v1.x, v1.y), pk2(v1.z, v1.w) };
            reinterpret_cast<uint4*>(sc + roff)[tc] = w;
        }
    }
    float* pp = p + ((size_t)(b * SLOT1 + sp * 2 + half)) * Mn + tc * 8;
    float4 o0 = {acc[0], acc[1], acc[2], acc[3]};
    float4 o1 = {acc[4], acc[5], acc[6], acc[7]};
    *reinterpret_cast<float4*>(pp)     = o0;
    *reinterpret_cast<float4*>(pp + 4) = o1;
}

// ---- reduce partial slots -> masked, guarded reciprocal c[b][m]
// grid (Bn, 4): thread owns one column -> 256 blocks, coalesced 4B loads.
__global__ __launch_bounds__(256) void col_final_kernel(
        const float* __restrict__ p, const int* __restrict__ ncols,
        float* __restrict__ c, int slots) {
    const int b = blockIdx.x;
    const int m = blockIdx.y * 256 + threadIdx.x;
    float sum = 0.f;
    for (int k = 0; k < slots; ++k)
        sum += p[((size_t)(b * SLOT1 + k)) * Mn + m];
    const int nc = ncols[b];
    c[(size_t)b * Mn + m] = (m < nc && sum > 0.f) ? 1.f / sum : 0.f;
}

// ---- FUSED row-pass + col-pass over bf16 sc, one sweep, masked-aware:
// one WAVE per row (16 rows/wave, grid (B,16), 4 waves/block). Rows >= nrows
// skipped entirely (their factor is 0); lane loads beyond ncols skipped
// (c=0 there; partials masked downstream). r never touches memory.
__global__ __launch_bounds__(256) void rowcol_kernel(
        const unsigned short* __restrict__ sc, const float* __restrict__ c,
        const int* __restrict__ nrows, const int* __restrict__ ncols,
        float* __restrict__ p) {
    const int b = blockIdx.x;
    const int t = threadIdx.x, w = t >> 6, l = t & 63;
    const int n0 = blockIdx.y * 64 + w * 16;
    const int nr = nrows[b], nc = ncols[b];
    const float4* cb = reinterpret_cast<const float4*>(c + (size_t)b * Mn);
    const float4 c0 = cb[2 * l], c1 = cb[2 * l + 1];
    const float4 c2 = cb[128 + 2 * l], c3 = cb[128 + 2 * l + 1];
    const bool lo_ok = (8 * l) < nc;
    const bool hi_ok = (512 + 8 * l) < nc;
    const uint4 z4 = {0u, 0u, 0u, 0u};
    float acc[16];
    #pragma unroll
    for (int k = 0; k < 16; ++k) acc[k] = 0.f;
    for (int j = 0; j < 16; ++j) {
        const int n = n0 + j;
        if (n >= nr) break;
        const uint4* row = reinterpret_cast<const uint4*>(sc + ((size_t)b * Nn + n) * Mn);
        uint4 a = lo_ok ? row[l] : z4;
        uint4 d = hi_ok ? row[64 + l] : z4;
        const float v0 = lo16(a.x), v1 = hi16(a.x), v2 = lo16(a.y), v3 = hi16(a.y);
        const float v4 = lo16(a.z), v5 = hi16(a.z), v6 = lo16(a.w), v7 = hi16(a.w);
        const float v8 = lo16(d.x), v9 = hi16(d.x), v10 = lo16(d.y), v11 = hi16(d.y);
        const float v12 = lo16(d.z), v13 = hi16(d.z), v14 = lo16(d.w), v15 = hi16(d.w);
        float part = v0 * c0.x + v1 * c0.y + v2 * c0.z + v3 * c0.w
                   + v4 * c1.x + v5 * c1.y + v6 * c1.z + v7 * c1.w
                   + v8 * c2.x + v9 * c2.y + v10 * c2.z + v11 * c2.w
                   + v12 * c3.x + v13 * c3.y + v14 * c3.z + v15 * c3.w;
        #pragma unroll
        for (int off = 1; off < 64; off <<= 1) part += __shfl_xor(part, off, 64);
        const float rv = (part > 0.f) ? 1.f / part : 0.f;
        acc[0]  += v0 * rv;  acc[1]  += v1 * rv;  acc[2]  += v2 * rv;  acc[3]  += v3 * rv;
        acc[4]  += v4 * rv;  acc[5]  += v5 * rv;  acc[6]  += v6 * rv;  acc[7]  += v7 * rv;
        acc[8]  += v8 * rv;  acc[9]  += v9 * rv;  acc[10] += v10 * rv; acc[11] += v11 * rv;
        acc[12] += v12 * rv; acc[13] += v13 * rv; acc[14] += v14 * rv; acc[15] += v15 * rv;
    }
    float* pp = p + ((size_t)(b * SLOT1) + blockIdx.y * 4 + w) * Mn;
    float4 o;
    o = {acc[0], acc[1], acc[2], acc[3]};     *reinterpret_cast<float4*>(pp + 8 * l)           = o;
    o = {acc[4], acc[5], acc[6], acc[7]};     *reinterpret_cast<float4*>(pp + 8 * l + 4)       = o;
    o = {acc[8], acc[9], acc[10], acc[11]};   *reinterpret_cast<float4*>(pp + 512 + 8 * l)     = o;
    o = {acc[12], acc[13], acc[14], acc[15]}; *reinterpret_cast<float4*>(pp + 512 + 8 * l + 4) = o;
}

// ---- final pass: f32 s (exact values), last row factor in-wave, write out.
// Rows >= nrows: write zeros, no read. Col chunks >= ncols: skip load
// (c=0 makes the output 0 regardless).
__global__ __launch_bounds__(256) void final_kernel(
        const float* __restrict__ s, const float* __restrict__ c,
        const int* __restrict__ nrows, const int* __restrict__ ncols,
        float* __restrict__ out) {
    const int b = blockIdx.x;
    const int t = threadIdx.x, w = t >> 6, l = t & 63;
    const int n0 = blockIdx.y * 32 + w * 8;
    const int nr = nrows[b], nc = ncols[b];
    const float4* cb = reinterpret_cast<const float4*>(c + (size_t)b * Mn);
    float4 cc[4];
    bool ok[4];
    #pragma unroll
    for (int k = 0; k < 4; ++k) {
        cc[k] = cb[64 * k + l];
        ok[k] = (256 * k + 4 * l) < nc;
    }
    const float4 zf = {0.f, 0.f, 0.f, 0.f};
    for (int j = 0; j < 8; ++j) {
        const int n = n0 + j;
        const size_t roff = ((size_t)b * Nn + n) * Mn;
        float4* orow = reinterpret_cast<float4*>(out + roff);
        if (n >= nr) {
            #pragma unroll
            for (int k = 0; k < 4; ++k) orow[64 * k + l] = zf;
            continue;
        }
        const float4* row = reinterpret_cast<const float4*>(s + roff);
        float4 a[4];
        float part = 0.f;
        #pragma unroll
        for (int k = 0; k < 4; ++k) {
            a[k] = ok[k] ? row[64 * k + l] : zf;
            a[k].x += EPS; a[k].y += EPS; a[k].z += EPS; a[k].w += EPS;
            part += a[k].x * cc[k].x + a[k].y * cc[k].y
                  + a[k].z * cc[k].z + a[k].w * cc[k].w;
        }
        #pragma unroll
        for (int off = 1; off < 64; off <<= 1) part += __shfl_xor(part, off, 64);
        const float rv = (part > 0.f) ? 1.f / part : 0.f;
        #pragma unroll
        for (int k = 0; k < 4; ++k) {
            float4 o;
            o.x = a[k].x * cc[k].x * rv;
            o.y = a[k].y * cc[k].y * rv;
            o.z = a[k].z * cc[k].z * rv;
            o.w = a[k].w * cc[k].w * rv;
            orow[64 * k + l] = o;
        }
    }
}

extern "C" void kernel_launch(void* const* d_in, const int* in_sizes, int n_in,
                              void* d_out, int out_size, void* d_ws, size_t ws_size,
                              hipStream_t stream) {
    const float* s     = (const float*)d_in[0];
    const int*   nrows = (const int*)d_in[1];
    const int*   ncols = (const int*)d_in[2];
    float* out = (float*)d_out;

    // workspace: sc bf16 [B*N*M] (128 MiB) | p [B*SLOT1*M] (16 MB) | c (256 KB)
    unsigned short* sc = (unsigned short*)d_ws;
    float* p = (float*)(sc + (size_t)Bn * Nn * Mn);
    float* c = p + (size_t)Bn * SLOT1 * Mn;

    // i=0: col pass fused with bf16 compression of valid rows (unmasked sums)
    fuse0_kernel<<<dim3(Bn, NSPLIT), 256, 0, stream>>>(s, sc, p, nrows);
    col_final_kernel<<<dim3(Bn, 4), 256, 0, stream>>>(p, ncols, c, SLOT0);
    // i=1..8: four fused (row-norm + col-norm) sweeps over live region of sc
    for (int it = 0; it < 4; ++it) {
        rowcol_kernel<<<dim3(Bn, Nn / 64), 256, 0, stream>>>(sc, c, nrows, ncols, p);
        col_final_kernel<<<dim3(Bn, 4), 256, 0, stream>>>(p, ncols, c, SLOT1);
    }
    // i=9: final row normalization fused with output write (f32 precision)
    final_kernel<<<dim3(Bn, Nn / 32), 256, 0, stream>>>(s, c, nrows, ncols, out);
}